// Round 8
// baseline (242.851 us; speedup 1.0000x reference)
//
#include <hip/hip_runtime.h>

// LengthRegulator: B=32, T=1024, D=384, T_OUT=4096
// out[b, p, :] = x[b, t(p), :] where t(p) = #{t : ends[t] <= p} (searchsorted
// right of inclusive-cumsum of max(dur,0)), valid for p < min(total, target).
//
// Single fused kernel, 512-thread blocks covering exactly 64 output rows each
// (2048 blocks total): each block recomputes the cheap L2-resident duration
// scan itself, searches its 64 rows, then streams 12 float4/thread with
// wave-contiguous non-temporal stores.

#define BB 32
#define TT 1024
#define TOUT 4096
#define D4 96                // float4 per row (384/4)
#define N4 (TOUT * D4)       // 393216 float4 per batch
#define NTHR 512
#define EPB 6144             // float4 per block = exactly 64 rows
#define ROWS_PB 64
#define KPT 12               // float4 per thread (EPB / NTHR)

typedef float v4f __attribute__((ext_vector_type(4)));

__global__ __launch_bounds__(NTHR) void lr_fused(
    const int4* __restrict__ dur4,      // [B, 256] (durations viewed as int4)
    const int* __restrict__ target_len, // [B]
    const v4f* __restrict__ x,          // [B, T, D4]
    v4f* __restrict__ out)              // [B, TOUT, D4]
{
    __shared__ int s_ends[TT];
    __shared__ int s_wsum[4];
    __shared__ int s_trow[ROWS_PB];
    const int b = blockIdx.y;
    const int tid = threadIdx.x;
    const int lane = tid & 63;
    const int wave = tid >> 6;
    const int base0 = blockIdx.x * EPB;
    const int p0 = blockIdx.x * ROWS_PB;

    const int tl = target_len[b];               // hoisted, hides under scan

    // ---- in-block duration scan: threads 0..255 hold 4 durations each ----
    if (tid < 256) {
        int4 d = dur4[b * 256 + tid];
        const int d0 = d.x > 0 ? d.x : 0;
        const int d1 = d.y > 0 ? d.y : 0;
        const int d2 = d.z > 0 ? d.z : 0;
        const int d3 = d.w > 0 ? d.w : 0;
        const int e0 = d0, e1 = e0 + d1, e2 = e1 + d2, e3 = e2 + d3;

        // 64-lane inclusive scan of per-thread sums (6 shuffle steps)
        int v = e3;
        #pragma unroll
        for (int off = 1; off < 64; off <<= 1) {
            int u = __shfl_up(v, off, 64);
            if (lane >= off) v += u;
        }
        if (lane == 63) s_wsum[wave] = v;
        __syncthreads();

        int wbase = 0;
        #pragma unroll
        for (int w = 0; w < 3; ++w) wbase += (w < wave) ? s_wsum[w] : 0;

        const int base = wbase + v - e3;  // exclusive prefix for these 4
        ((int4*)s_ends)[tid] =
            make_int4(base + e0, base + e1, base + e2, base + e3);
        __syncthreads();
    } else {
        __syncthreads();
        __syncthreads();
    }

    const int total = s_ends[TT - 1];
    const int lim = total < tl ? total : tl;

    // ---- one binary search per output row this block covers ----
    if (tid < ROWS_PB) {
        const int p = p0 + tid;
        int lo = 0;
        #pragma unroll
        for (int s = 512; s > 0; s >>= 1) {
            lo += (s_ends[lo + s - 1] <= p) ? s : 0;   // lo stays in [0,1023]
        }
        s_trow[tid] = lo;
    }
    __syncthreads();

    // ---- gather: 12 float4/thread strided by 512 (wave-contiguous 1 KB
    // per store instruction -> full HBM lines, NT-safe; 12 loads in flight)
    const v4f* __restrict__ x_b = x + b * TT * D4;
    v4f* __restrict__ out_b = out + b * N4;

    int pp[KPT], cc[KPT], tt[KPT];
    v4f vv[KPT];
    #pragma unroll
    for (int k = 0; k < KPT; ++k) {
        const int i = base0 + k * NTHR + tid;
        const int p = i / D4;            // magic-mul division
        pp[k] = p;
        cc[k] = i - p * D4;
        tt[k] = s_trow[p - p0];          // LDS broadcast
    }
    #pragma unroll
    for (int k = 0; k < KPT; ++k) {
        vv[k] = x_b[tt[k] * D4 + cc[k]];
    }
    #pragma unroll
    for (int k = 0; k < KPT; ++k) {
        if (pp[k] >= lim) vv[k] = (v4f)(0.f);
        __builtin_nontemporal_store(vv[k], out_b + base0 + k * NTHR + tid);
    }
}

extern "C" void kernel_launch(void* const* d_in, const int* in_sizes, int n_in,
                              void* d_out, int out_size, void* d_ws, size_t ws_size,
                              hipStream_t stream) {
    const float* x        = (const float*)d_in[0];
    const int* durations  = (const int*)d_in[1];
    const int* target_len = (const int*)d_in[2];
    float* out            = (float*)d_out;

    dim3 grid(N4 / EPB, BB);  // 64 x 32 blocks
    lr_fused<<<grid, NTHR, 0, stream>>>((const int4*)durations, target_len,
                                        (const v4f*)x, (v4f*)out);
}